// Round 7
// baseline (285.288 us; speedup 1.0000x reference)
//
#include <hip/hip_runtime.h>

// image (8,256,64,64) f32, boxes (1000,4) f32, box_ind (1000,) i32
// out (1000,256,14,14) f32
constexpr int CROP_H = 14;
constexpr int CROP_W = 14;
constexpr int PIX    = CROP_H * CROP_W;   // 196
constexpr int IMG_C  = 256;
constexpr int IMG_H  = 64;
constexpr int IMG_W  = 64;
constexpr int N_IMG  = 8;
constexpr int N_BOX  = 1000;
constexpr int CH_WG  = 4;                 // channel planes staged per workgroup
constexpr int NWG    = N_IMG * (IMG_C / CH_WG);  // 8 * 64 = 512 (2 per CU)

// R6 post-mortem: cache-shaping (XCD pinning, capacity, MLP) all null ->
// kernel is fetch-volume-bound (~250-290MB vs 33.5MB unique image bytes).
// New structure eliminates overfetch by construction: each WG stages 4 full
// channel planes of one image into LDS (64KB) ONCE, then computes every box
// of that image from LDS. Total HBM fetch = 512 x 64KB = 33MB exactly.
// Writes (200MB, NT, coalesced) become the floor: ~31us @ 6.5TB/s.
typedef float f2 __attribute__((ext_vector_type(2), aligned(4)));

__global__ __launch_bounds__(256) void CropAndResize_5669356832751_kernel(
    const float* __restrict__ image,
    const float* __restrict__ boxes,
    const int*   __restrict__ box_ind,
    float* __restrict__ out)
{
    __shared__ float lds[CH_WG][IMG_H][IMG_W];   // 64 KB -> 2 WGs/CU

    const int wg    = blockIdx.x;
    const int img   = wg & (N_IMG - 1);          // this WG's image
    const int c0    = (wg >> 3) * CH_WG;         // first channel of its chunk

    // ---- Stage 4 channel planes (64 KB), fully coalesced float4 copy ----
    {
        const float4* src = reinterpret_cast<const float4*>(
            image + ((size_t)img * IMG_C + c0) * (size_t)(IMG_H * IMG_W));
        float4* d = reinterpret_cast<float4*>(&lds[0][0][0]);
        constexpr int NV = CH_WG * IMG_H * IMG_W / 4;   // 4096 float4s
#pragma unroll
        for (int i = 0; i < NV / 256; ++i)              // 16 iters
            d[i * 256 + threadIdx.x] = src[i * 256 + threadIdx.x];
    }
    __syncthreads();

    // Per-thread crop pixel (threads 196..255 idle in compute, help staging)
    const int  px  = threadIdx.x;
    const int  y   = px / CROP_W;
    const int  x   = px - y * CROP_W;
    const bool act = (px < PIX);

    // ---- Loop over all boxes; process those belonging to this image ----
    int4 nxt = *reinterpret_cast<const int4*>(box_ind);  // prefetched, uniform
    for (int nb = 0; nb < N_BOX; nb += 4) {
        const int4 cur = nxt;
        if (nb + 4 < N_BOX)
            nxt = *reinterpret_cast<const int4*>(box_ind + nb + 4);
        const int bi4[4] = {cur.x, cur.y, cur.z, cur.w};
#pragma unroll
        for (int j = 0; j < 4; ++j) {
            if (bi4[j] != img) continue;                 // uniform branch
            const int n = nb + j;
            const float4 bx = *reinterpret_cast<const float4*>(boxes + 4 * n);
            if (!act) continue;

            const float y1 = bx.x, x1 = bx.y, y2 = bx.z, x2 = bx.w;
            const float hs = (y2 - y1) * (63.0f / 13.0f);
            const float ws = (x2 - x1) * (63.0f / 13.0f);
            const float in_y = y1 * 63.0f + (float)y * hs;
            const float in_x = x1 * 63.0f + (float)x * ws;

            const bool oob = (in_y < 0.0f) | (in_y > 63.0f) |
                             (in_x < 0.0f) | (in_x > 63.0f);

            // Shifted 2x2 window: row0,col0 in [0,62]; effective lerp from the
            // window origin reproduces clamped-tap semantics exactly.
            const int ti = (int)fminf(fmaxf(floorf(in_y), 0.0f), 63.0f);
            const int li = (int)fminf(fmaxf(floorf(in_x), 0.0f), 63.0f);
            const int row0 = min(ti, 62);
            const int col0 = min(li, 62);
            const float yl = fminf(fmaxf(in_y, 0.0f), 63.0f) - (float)row0;
            const float xl = fminf(fmaxf(in_x, 0.0f), 63.0f) - (float)col0;

            const float m    = oob ? 0.0f : 1.0f;
            const float omxl = 1.0f - xl;
            const float omyl = 1.0f - yl;
            const float w00 = omxl * omyl * m;
            const float w01 = xl   * omyl * m;
            const float w10 = omxl * yl   * m;
            const float w11 = xl   * yl   * m;

            const float* lp  = &lds[0][row0][col0];
            float*       dst = out + ((size_t)n * IMG_C + c0) * (size_t)PIX + px;
#pragma unroll
            for (int ch = 0; ch < CH_WG; ++ch) {
                const float* q = lp + ch * (IMG_H * IMG_W);
                f2 t  = *reinterpret_cast<const f2*>(q);          // v00, v01
                f2 bo = *reinterpret_cast<const f2*>(q + IMG_W);  // v10, v11
                float v = t.x * w00 + t.y * w01 + bo.x * w10 + bo.y * w11;
                __builtin_nontemporal_store(v, dst + ch * PIX);
            }
        }
    }
}

extern "C" void kernel_launch(void* const* d_in, const int* in_sizes, int n_in,
                              void* d_out, int out_size, void* d_ws, size_t ws_size,
                              hipStream_t stream) {
    const float* image   = (const float*)d_in[0];
    const float* boxes   = (const float*)d_in[1];
    const int*   box_ind = (const int*)d_in[2];
    float* out = (float*)d_out;

    CropAndResize_5669356832751_kernel<<<dim3(NWG), 256, 0, stream>>>(
        image, boxes, box_ind, out);
}

// Round 8
// 259.981 us; speedup vs baseline: 1.0973x; 1.0973x over previous
//
#include <hip/hip_runtime.h>

// image (8,256,64,64) f32, boxes (1000,4) f32, box_ind (1000,) i32
// out (1000,256,14,14) f32
constexpr int CROP_H = 14;
constexpr int CROP_W = 14;
constexpr int PIX    = CROP_H * CROP_W;   // 196
constexpr int IMG_C  = 256;
constexpr int IMG_H  = 64;
constexpr int IMG_W  = 64;
constexpr int PLANE  = IMG_H * IMG_W;     // 4096
constexpr int N_IMG  = 8;
constexpr int N_BOX  = 1000;
constexpr int CH_WG  = 2;                 // channels staged per WG (interleaved)
constexpr int NCHUNK = IMG_C / CH_WG;     // 128
constexpr int NWG    = N_IMG * NCHUNK;    // 1024 WGs -> 4/CU, full residency
constexpr int LDS_W  = 66;                // padded row stride (dword-pairs)

// R7 post-mortem: perfect-fetch LDS version ran at ~123us because of 25%
// occupancy + 250-iter wasted scan + row-independent LDS bank conflicts
// (row stride 64 dwords == 0 mod 32 -> bank = col mod 32). Fixes:
//  - f2v lds[64][66]: channel-pair interleave -> 1 ds_read_b64 per tap
//    (4 reads/box, was 8), row stride 132 dwords -> banks spread by row.
//  - 33.8 KB LDS -> 4 WG/CU = 16 waves/CU (2x R7), 1024 WGs exact fit.
//  - prepass bins boxes per image into d_ws -> dense inner loop, uniform
//    scalar list/box loads (fallback scan if ws too small).
typedef float f2v __attribute__((ext_vector_type(2)));  // 8B-aligned pair

constexpr size_t WS_INTS = 8 + (size_t)N_IMG * N_BOX;   // counts + lists

__global__ __launch_bounds__(1024) void crop_prepass(
    const int* __restrict__ box_ind, int* __restrict__ ws)
{
    __shared__ int cnt[N_IMG];
    if (threadIdx.x < N_IMG) cnt[threadIdx.x] = 0;
    __syncthreads();
    const int n = threadIdx.x;
    if (n < N_BOX) {
        const int img  = box_ind[n];
        const int slot = atomicAdd(&cnt[img], 1);
        ws[8 + img * N_BOX + slot] = n;
    }
    __syncthreads();
    if (threadIdx.x < N_IMG) ws[threadIdx.x] = cnt[threadIdx.x];
}

template<bool USE_LIST>
__global__ __launch_bounds__(256) void CropAndResize_5669356832751_kernel(
    const float* __restrict__ image,
    const float* __restrict__ boxes,
    const int*   __restrict__ box_ind,
    const int*   __restrict__ ws,
    float* __restrict__ out)
{
    __shared__ f2v lds[IMG_H][LDS_W];     // 33,792 B

    const int wg  = blockIdx.x;
    const int img = wg & (N_IMG - 1);
    const int c0  = (wg >> 3) * CH_WG;

    // ---- stage 2 channel planes, interleaved; coalesced 4B global reads,
    //      ds_write_b64 with 2-way (free) bank aliasing ----
    const float* p0 = image + ((size_t)img * IMG_C + c0) * PLANE;
    const float* p1 = p0 + PLANE;
    for (int flat = threadIdx.x; flat < PLANE; flat += 256) {
        const int row = flat >> 6, col = flat & 63;
        f2v v; v.x = p0[flat]; v.y = p1[flat];
        lds[row][col] = v;
    }
    __syncthreads();

    const int  px  = threadIdx.x;
    const int  y   = px / CROP_W;
    const int  x   = px - y * CROP_W;
    const bool act = (px < PIX);

    const int  nloop = USE_LIST ? ws[img] : N_BOX;
    const int* list  = ws + 8 + img * N_BOX;

    for (int i = 0; i < nloop; ++i) {
        int n;
        if (USE_LIST) {
            n = list[i];                          // uniform scalar load
        } else {
            n = i;
            if (box_ind[n] != img) continue;      // uniform branch
        }
        const float4 bx = *reinterpret_cast<const float4*>(boxes + 4 * n);

        if (act) {
            const float y1 = bx.x, x1 = bx.y, y2 = bx.z, x2 = bx.w;
            const float hs = (y2 - y1) * (63.0f / 13.0f);
            const float ws_ = (x2 - x1) * (63.0f / 13.0f);
            const float in_y = y1 * 63.0f + (float)y * hs;
            const float in_x = x1 * 63.0f + (float)x * ws_;

            const bool oob = (in_y < 0.0f) | (in_y > 63.0f) |
                             (in_x < 0.0f) | (in_x > 63.0f);

            // Shifted 2x2 window: row0,col0 in [0,62]; lerp from the window
            // origin reproduces clamped-tap semantics exactly (verified).
            const int ti = (int)fminf(fmaxf(floorf(in_y), 0.0f), 63.0f);
            const int li = (int)fminf(fmaxf(floorf(in_x), 0.0f), 63.0f);
            const int row0 = min(ti, 62);
            const int col0 = min(li, 62);
            const float yl = fminf(fmaxf(in_y, 0.0f), 63.0f) - (float)row0;
            const float xl = fminf(fmaxf(in_x, 0.0f), 63.0f) - (float)col0;

            const float m    = oob ? 0.0f : 1.0f;
            const float omxl = 1.0f - xl;
            const float omyl = 1.0f - yl;
            const float w00 = omxl * omyl * m;
            const float w01 = xl   * omyl * m;
            const float w10 = omxl * yl   * m;
            const float w11 = xl   * yl   * m;

            const f2v t00 = lds[row0][col0];
            const f2v t01 = lds[row0][col0 + 1];
            const f2v t10 = lds[row0 + 1][col0];
            const f2v t11 = lds[row0 + 1][col0 + 1];
            const float v0 = t00.x * w00 + t01.x * w01 + t10.x * w10 + t11.x * w11;
            const float v1 = t00.y * w00 + t01.y * w01 + t10.y * w10 + t11.y * w11;

            float* dst = out + ((size_t)n * IMG_C + c0) * PIX + px;
            __builtin_nontemporal_store(v0, dst);
            __builtin_nontemporal_store(v1, dst + PIX);
        }
    }
}

extern "C" void kernel_launch(void* const* d_in, const int* in_sizes, int n_in,
                              void* d_out, int out_size, void* d_ws, size_t ws_size,
                              hipStream_t stream) {
    const float* image   = (const float*)d_in[0];
    const float* boxes   = (const float*)d_in[1];
    const int*   box_ind = (const int*)d_in[2];
    float* out = (float*)d_out;
    int*   ws  = (int*)d_ws;

    const bool use_list = (ws != nullptr) && (ws_size >= WS_INTS * sizeof(int));
    if (use_list) {
        crop_prepass<<<dim3(1), 1024, 0, stream>>>(box_ind, ws);
        CropAndResize_5669356832751_kernel<true><<<dim3(NWG), 256, 0, stream>>>(
            image, boxes, box_ind, ws, out);
    } else {
        CropAndResize_5669356832751_kernel<false><<<dim3(NWG), 256, 0, stream>>>(
            image, boxes, box_ind, ws, out);
    }
}